// Round 7
// baseline (89.938 us; speedup 1.0000x reference)
//
#include <hip/hip_runtime.h>
#include <hip/hip_bf16.h>

// z[b, k] = sum_{e : K[e]==k} x[b, I[e]] * y[b, J[e]] * C[e]
// B=2048, DIM=248, N_ENTRIES=60000.
//
// R7: k_main was ~30us of the 46.6 (random-index float4 LDS gathers: 64B/entry
// -lane + ~2x bank conflicts). Rewrite as broadcast-gather:
//   - LDS layout xs[c*32 + row] (32 rows/block): a half-wave's 32 lanes read
//     xs[i*32 + r] -> bank = r%32 -> 2 lanes/bank = conflict-FREE (m136).
//   - Wave processes one bucket; halves process different entries in the same
//     instruction (2 entries per VALU op). int4 bulk meta loads (4 entries per
//     half per iter, unpredicated) + small predicated tail.
//   - Register accumulation, __shfl_xor(32) combine, direct store. No atomics.
// Scatter now packs pre-scaled offsets: (i*32) | (j*32 << 16).
// Pipeline: k_zero -> k_scatter -> k_main.

#define DIM 248
#define CAP 1024     // slots per bucket (binomial max ~292 for this input)
#define ROWS 32      // batch rows per main block
#define KS 8         // k-slices per batch group
#define KPB 31       // DIM/KS
#define BLOCK 256

typedef unsigned int uint32;

// ---------- zero: 4096 cursor words ----------
__global__ __launch_bounds__(BLOCK) void k_zero(uint32* __restrict__ cur) {
  cur[blockIdx.x * BLOCK + threadIdx.x] = 0u;
}

// ---------- scatter: 1 thread/entry, atomic cursor, fixed-capacity buckets ----------
__global__ __launch_bounds__(BLOCK) void k_scatter(
    const int* __restrict__ I, const int* __restrict__ J,
    const int* __restrict__ K, const float* __restrict__ C,
    uint32* __restrict__ cur, int2* __restrict__ IJC, int n) {
  const int e = blockIdx.x * BLOCK + threadIdx.x;
  if (e >= n) return;
  const int k = K[e];
  const uint32 pos = atomicAdd(&cur[k * 16], 1u);   // cursors 64 B apart
  if (pos < CAP) {
    int2 v;
    v.x = ((I[e] & 255) << 5) | ((J[e] & 255) << 21);  // i*32 | (j*32)<<16
    v.y = __float_as_int(C[e]);
    IJC[(size_t)k * CAP + pos] = v;
  }
}

// ---------- main: broadcast-gather, conflict-free LDS, no atomics ----------
__global__ __launch_bounds__(BLOCK, 2) void k_main(
    const float* __restrict__ x, const float* __restrict__ y,
    const int2* __restrict__ IJC, const uint32* __restrict__ cur,
    float* __restrict__ z, int B) {
  __shared__ float xs[DIM * ROWS];   // xs[c*32 + row]
  __shared__ float ys[DIM * ROWS];
  __shared__ uint32 rp[KPB];

  const int t = threadIdx.x;
  const int group = blockIdx.x / KS;   // 32-row group
  const int slice = blockIdx.x % KS;   // k-slice
  const int b0 = group * ROWS;
  const int k0 = slice * KPB;

  // Stage x,y transposed: thread -> row = t&31, c4 walks columns.
  // LDS writes: bank = row%32, each bank 2 lanes -> conflict-free.
  {
    const int row = t & 31;
    const int bb = b0 + row < B ? b0 + row : B - 1;
    const float* xrow = x + (size_t)bb * DIM;
    const float* yrow = y + (size_t)bb * DIM;
    for (int c4 = t >> 5; c4 < DIM / 4; c4 += BLOCK / 32) {
      const float4 vx = *(const float4*)(xrow + c4 * 4);
      const float4 vy = *(const float4*)(yrow + c4 * 4);
      const int cb = c4 * 4;
      xs[(cb + 0) * ROWS + row] = vx.x;
      xs[(cb + 1) * ROWS + row] = vx.y;
      xs[(cb + 2) * ROWS + row] = vx.z;
      xs[(cb + 3) * ROWS + row] = vx.w;
      ys[(cb + 0) * ROWS + row] = vy.x;
      ys[(cb + 1) * ROWS + row] = vy.y;
      ys[(cb + 2) * ROWS + row] = vy.z;
      ys[(cb + 3) * ROWS + row] = vy.w;
    }
  }
  if (t < KPB) {
    uint32 c = cur[(k0 + t) * 16];
    rp[t] = c < CAP ? c : CAP;
  }
  __syncthreads();

  const int wave = t >> 6;   // 0..3
  const int lane = t & 63;
  const int h = lane >> 5;   // half id: which entry stream
  const int r = lane & 31;   // row within group
  const int b = b0 + r;

  for (int kk = wave; kk < KPB; kk += 4) {
    const uint32 s0 = (uint32)(k0 + kk) * CAP;
    const uint32 cnt = rp[kk];
    float acc0 = 0.f, acc1 = 0.f;

    // Bulk: 8 entries/iter (4 per half), unpredicated int4 loads (2 entries each).
    uint32 tt = 0;
    for (; tt + 8 <= cnt; tt += 8) {
      const uint32 rel = tt + h * 4;
      const int4 ma = *(const int4*)&IJC[s0 + rel];       // entries rel, rel+1
      const int4 mb = *(const int4*)&IJC[s0 + rel + 2];   // entries rel+2, rel+3
      {
        const int w = ma.x;  const float cc = __int_as_float(ma.y);
        acc0 = fmaf(xs[(w & 0xFFFF) + r] * ys[(w >> 16) + r], cc, acc0);
      }
      {
        const int w = ma.z;  const float cc = __int_as_float(ma.w);
        acc1 = fmaf(xs[(w & 0xFFFF) + r] * ys[(w >> 16) + r], cc, acc1);
      }
      {
        const int w = mb.x;  const float cc = __int_as_float(mb.y);
        acc0 = fmaf(xs[(w & 0xFFFF) + r] * ys[(w >> 16) + r], cc, acc0);
      }
      {
        const int w = mb.z;  const float cc = __int_as_float(mb.w);
        acc1 = fmaf(xs[(w & 0xFFFF) + r] * ys[(w >> 16) + r], cc, acc1);
      }
    }
    // Tail: up to 7 entries, predicated singles (4 slots per half).
    {
      const uint32 rel0 = tt + h * 4;
#pragma unroll
      for (int u = 0; u < 4; ++u) {
        const uint32 rel = rel0 + u;
        if (rel < cnt) {
          const int2 m = IJC[s0 + rel];
          const int w = m.x;  const float cc = __int_as_float(m.y);
          acc0 = fmaf(xs[(w & 0xFFFF) + r] * ys[(w >> 16) + r], cc, acc0);
        }
      }
    }

    float s = acc0 + acc1;
    s += __shfl_xor(s, 32, 64);   // combine the two half-streams
    if (h == 0 && b < B) z[(size_t)b * DIM + (k0 + kk)] = s;
  }
}

// ---------- Fallback (R2 kernel) if workspace is too small ----------
__global__ __launch_bounds__(BLOCK) void k_fallback(
    const float* __restrict__ x, const float* __restrict__ y,
    const int* __restrict__ I, const int* __restrict__ J,
    const int* __restrict__ K, const float* __restrict__ C,
    float* __restrict__ z, int n_entries, int B) {
  __shared__ float4 xs[DIM];
  __shared__ float4 ys[DIM];
  __shared__ float zs[DIM][4];
  const int t = threadIdx.x;
  const int group = blockIdx.x / 4;
  const int slice = blockIdx.x % 4;
  const int b0 = group * 4;
  for (int c = t; c < DIM; c += BLOCK) {
    float4 vx, vy;
    vx.x = x[(b0 + 0) * DIM + c];  vy.x = y[(b0 + 0) * DIM + c];
    vx.y = x[(b0 + 1) * DIM + c];  vy.y = y[(b0 + 1) * DIM + c];
    vx.z = x[(b0 + 2) * DIM + c];  vy.z = y[(b0 + 2) * DIM + c];
    vx.w = x[(b0 + 3) * DIM + c];  vy.w = y[(b0 + 3) * DIM + c];
    xs[c] = vx;  ys[c] = vy;
    zs[c][0] = 0.f; zs[c][1] = 0.f; zs[c][2] = 0.f; zs[c][3] = 0.f;
  }
  __syncthreads();
  const int n_per = ((n_entries + 3) / 4 + 3) & ~3;
  int e0 = slice * n_per;  if (e0 > n_entries) e0 = n_entries;
  int e1 = e0 + n_per;     if (e1 > n_entries) e1 = n_entries;
  for (int e = e0 + t; e < e1; e += BLOCK) {
    const int ii = I[e], jj = J[e], kk = K[e];
    const float c = C[e];
    const float4 vx = xs[ii], vy = ys[jj];
    atomicAdd(&zs[kk][0], vx.x * vy.x * c);
    atomicAdd(&zs[kk][1], vx.y * vy.y * c);
    atomicAdd(&zs[kk][2], vx.z * vy.z * c);
    atomicAdd(&zs[kk][3], vx.w * vy.w * c);
  }
  __syncthreads();
  for (int i = t; i < 4 * DIM; i += BLOCK) {
    const int r = i / DIM, c = i % DIM;
    const int b = b0 + r;
    if (b < B) atomicAdd(&z[b * DIM + c], zs[c][r]);
  }
}

extern "C" void kernel_launch(void* const* d_in, const int* in_sizes, int n_in,
                              void* d_out, int out_size, void* d_ws, size_t ws_size,
                              hipStream_t stream) {
  const float* x = (const float*)d_in[0];
  const float* y = (const float*)d_in[1];
  const int* I = (const int*)d_in[2];
  const int* J = (const int*)d_in[3];
  const int* K = (const int*)d_in[4];
  const float* C = (const float*)d_in[5];
  float* z = (float*)d_out;

  const int n = in_sizes[2];
  const int B = in_sizes[0] / DIM;

  // ws layout: cur[248*16 uint32, padded cursors] (16 KB region) | IJC[248*CAP int2]
  const size_t cur_words = 4096;
  const size_t cur_bytes = cur_words * sizeof(uint32);          // 16 KB
  const size_t needed = cur_bytes + (size_t)DIM * CAP * 8;      // + ~2 MB
  if (ws_size < needed) {
    hipMemsetAsync(d_out, 0, (size_t)B * DIM * sizeof(float), stream);
    const int grid = ((B + 3) / 4) * 4;
    k_fallback<<<grid, BLOCK, 0, stream>>>(x, y, I, J, K, C, z, n, B);
    return;
  }

  uint32* cur = (uint32*)d_ws;
  int2* IJC = (int2*)((char*)d_ws + cur_bytes);   // 8B-aligned

  k_zero<<<cur_words / BLOCK, BLOCK, 0, stream>>>(cur);
  k_scatter<<<(n + BLOCK - 1) / BLOCK, BLOCK, 0, stream>>>(I, J, K, C, cur, IJC, n);

  const int groups = (B + ROWS - 1) / ROWS;
  k_main<<<groups * KS, BLOCK, 0, stream>>>(x, y, IJC, cur, z, B);
}

// Round 8
// 54.850 us; speedup vs baseline: 1.6397x; 1.6397x over previous
//
#include <hip/hip_runtime.h>
#include <hip/hip_bf16.h>

// z[b, k] = sum_{e : K[e]==k} x[b, I[e]] * y[b, J[e]] * C[e]
// B=2048, DIM=248, N_ENTRIES=60000.
//
// R8: R7's broadcast-gather was latency-bound (VALUBusy 25%, occ 19.7%,
// 2 entry-streams/wave, 64KB LDS -> 2 blocks/CU). Fix:
//   - ROWS 32->16: LDS 31.7KB -> 4 blocks/CU (16 waves/CU), and 4 quarter-wave
//     entry streams per wave (4x ILP). Gather stays ~conflict-free (16
//     consecutive banks per stream, ~2 lanes/bank avg = free per m136).
//   - k_zero clears cursors + whole IJC (1MB): buckets are zero-padded to a
//     multiple of 16 entries -> branch-free inner loop (pad slots: w=0,c=0
//     contribute exactly 0).
// Pipeline: k_zero -> k_scatter -> k_main. No atomics in main, no predication.

#define DIM 248
#define CAP 512      // slots/bucket (mean 242, sigma 15.5 -> 512 is ~17 sigma)
#define ROWS 16      // batch rows per main block
#define KS 8         // k-slices per batch group
#define KPB 31       // DIM/KS
#define BLOCK 256

typedef unsigned int uint32;

// ---------- zero: cursors (16KB) + IJC (1MB), one float4 store per thread ----------
#define ZERO_WORDS (4096 + DIM * CAP * 2)          // 258048 dwords
#define ZERO_VECS  (ZERO_WORDS / 4)                // 64512 int4 stores
__global__ __launch_bounds__(BLOCK) void k_zero(int4* __restrict__ ws) {
  const int i = blockIdx.x * BLOCK + threadIdx.x;
  if (i < ZERO_VECS) ws[i] = int4{0, 0, 0, 0};
}

// ---------- scatter: 1 thread/entry, atomic cursor, fixed-capacity buckets ----------
__global__ __launch_bounds__(BLOCK) void k_scatter(
    const int* __restrict__ I, const int* __restrict__ J,
    const int* __restrict__ K, const float* __restrict__ C,
    uint32* __restrict__ cur, int2* __restrict__ IJC, int n) {
  const int e = blockIdx.x * BLOCK + threadIdx.x;
  if (e >= n) return;
  const int k = K[e];
  const uint32 pos = atomicAdd(&cur[k * 16], 1u);   // cursors 64 B apart
  if (pos < CAP) {
    int2 v;
    v.x = ((I[e] & 255) << 4) | ((J[e] & 255) << 20);  // i*16 | (j*16)<<16
    v.y = __float_as_int(C[e]);
    IJC[(size_t)k * CAP + pos] = v;
  }
}

// ---------- main: broadcast-gather, 4 entry-streams/wave, branch-free ----------
__global__ __launch_bounds__(BLOCK, 4) void k_main(
    const float* __restrict__ x, const float* __restrict__ y,
    const int2* __restrict__ IJC, const uint32* __restrict__ cur,
    float* __restrict__ z, int B) {
  __shared__ float xs[DIM * ROWS];   // xs[c*16 + row]
  __shared__ float ys[DIM * ROWS];
  __shared__ uint32 rp[KPB];

  const int t = threadIdx.x;
  const int group = blockIdx.x / KS;   // 16-row group
  const int slice = blockIdx.x % KS;   // k-slice
  const int b0 = group * ROWS;
  const int k0 = slice * KPB;

  // Stage x,y transposed: row = t&15, c4 = t>>4 walks float4 columns.
  {
    const int row = t & 15;
    const int bb = b0 + row < B ? b0 + row : B - 1;
    const float* xrow = x + (size_t)bb * DIM;
    const float* yrow = y + (size_t)bb * DIM;
    for (int c4 = t >> 4; c4 < DIM / 4; c4 += BLOCK / 16) {
      const float4 vx = *(const float4*)(xrow + c4 * 4);
      const float4 vy = *(const float4*)(yrow + c4 * 4);
      const int cb = c4 * 4;
      xs[(cb + 0) * ROWS + row] = vx.x;
      xs[(cb + 1) * ROWS + row] = vx.y;
      xs[(cb + 2) * ROWS + row] = vx.z;
      xs[(cb + 3) * ROWS + row] = vx.w;
      ys[(cb + 0) * ROWS + row] = vy.x;
      ys[(cb + 1) * ROWS + row] = vy.y;
      ys[(cb + 2) * ROWS + row] = vy.z;
      ys[(cb + 3) * ROWS + row] = vy.w;
    }
  }
  if (t < KPB) {
    const uint32 c = cur[(k0 + t) * 16];
    rp[t] = c < CAP ? c : CAP;
  }
  __syncthreads();

  const int wave = t >> 6;   // 0..3
  const int lane = t & 63;
  const int q = lane >> 4;   // quarter id: which entry stream
  const int r = lane & 15;   // row within group
  const int b = b0 + r;

  for (int kk = wave; kk < KPB; kk += 4) {
    const uint32 s0 = (uint32)(k0 + kk) * CAP;
    const uint32 cnt = rp[kk];
    const uint32 cntp = (cnt + 15u) & ~15u;   // <= CAP (CAP%16==0)
    float a0 = 0.f, a1 = 0.f, a2 = 0.f, a3 = 0.f;

    // 16 entries/wave/iter (4 per quarter via 2x int4); pad slots are zeros.
    for (uint32 tt = 0; tt < cntp; tt += 16) {
      const uint32 rel = s0 + tt + q * 4;
      const int4 ma = *(const int4*)&IJC[rel];       // entries rel, rel+1
      const int4 mb = *(const int4*)&IJC[rel + 2];   // entries rel+2, rel+3
      {
        const int w = ma.x;
        a0 = fmaf(xs[(w & 0xFFFF) + r] * ys[((uint32)w >> 16) + r],
                  __int_as_float(ma.y), a0);
      }
      {
        const int w = ma.z;
        a1 = fmaf(xs[(w & 0xFFFF) + r] * ys[((uint32)w >> 16) + r],
                  __int_as_float(ma.w), a1);
      }
      {
        const int w = mb.x;
        a2 = fmaf(xs[(w & 0xFFFF) + r] * ys[((uint32)w >> 16) + r],
                  __int_as_float(mb.y), a2);
      }
      {
        const int w = mb.z;
        a3 = fmaf(xs[(w & 0xFFFF) + r] * ys[((uint32)w >> 16) + r],
                  __int_as_float(mb.w), a3);
      }
    }

    float s = (a0 + a1) + (a2 + a3);
    s += __shfl_xor(s, 16, 64);   // combine quarters 0<->1, 2<->3
    s += __shfl_xor(s, 32, 64);   // combine halves
    if (q == 0 && b < B) z[(size_t)b * DIM + (k0 + kk)] = s;
  }
}

// ---------- Fallback (R2 kernel) if workspace is too small ----------
__global__ __launch_bounds__(BLOCK) void k_fallback(
    const float* __restrict__ x, const float* __restrict__ y,
    const int* __restrict__ I, const int* __restrict__ J,
    const int* __restrict__ K, const float* __restrict__ C,
    float* __restrict__ z, int n_entries, int B) {
  __shared__ float4 xs[DIM];
  __shared__ float4 ys[DIM];
  __shared__ float zs[DIM][4];
  const int t = threadIdx.x;
  const int group = blockIdx.x / 4;
  const int slice = blockIdx.x % 4;
  const int b0 = group * 4;
  for (int c = t; c < DIM; c += BLOCK) {
    float4 vx, vy;
    vx.x = x[(b0 + 0) * DIM + c];  vy.x = y[(b0 + 0) * DIM + c];
    vx.y = x[(b0 + 1) * DIM + c];  vy.y = y[(b0 + 1) * DIM + c];
    vx.z = x[(b0 + 2) * DIM + c];  vy.z = y[(b0 + 2) * DIM + c];
    vx.w = x[(b0 + 3) * DIM + c];  vy.w = y[(b0 + 3) * DIM + c];
    xs[c] = vx;  ys[c] = vy;
    zs[c][0] = 0.f; zs[c][1] = 0.f; zs[c][2] = 0.f; zs[c][3] = 0.f;
  }
  __syncthreads();
  const int n_per = ((n_entries + 3) / 4 + 3) & ~3;
  int e0 = slice * n_per;  if (e0 > n_entries) e0 = n_entries;
  int e1 = e0 + n_per;     if (e1 > n_entries) e1 = n_entries;
  for (int e = e0 + t; e < e1; e += BLOCK) {
    const int ii = I[e], jj = J[e], kk = K[e];
    const float c = C[e];
    const float4 vx = xs[ii], vy = ys[jj];
    atomicAdd(&zs[kk][0], vx.x * vy.x * c);
    atomicAdd(&zs[kk][1], vx.y * vy.y * c);
    atomicAdd(&zs[kk][2], vx.z * vy.z * c);
    atomicAdd(&zs[kk][3], vx.w * vy.w * c);
  }
  __syncthreads();
  for (int i = t; i < 4 * DIM; i += BLOCK) {
    const int r = i / DIM, c = i % DIM;
    const int b = b0 + r;
    if (b < B) atomicAdd(&z[b * DIM + c], zs[c][r]);
  }
}

extern "C" void kernel_launch(void* const* d_in, const int* in_sizes, int n_in,
                              void* d_out, int out_size, void* d_ws, size_t ws_size,
                              hipStream_t stream) {
  const float* x = (const float*)d_in[0];
  const float* y = (const float*)d_in[1];
  const int* I = (const int*)d_in[2];
  const int* J = (const int*)d_in[3];
  const int* K = (const int*)d_in[4];
  const float* C = (const float*)d_in[5];
  float* z = (float*)d_out;

  const int n = in_sizes[2];
  const int B = in_sizes[0] / DIM;

  // ws layout: cur[4096 uint32 padded cursors] (16 KB) | IJC[248*CAP int2] (1 MB)
  const size_t cur_bytes = 4096 * sizeof(uint32);
  const size_t needed = (size_t)ZERO_WORDS * 4;
  if (ws_size < needed) {
    hipMemsetAsync(d_out, 0, (size_t)B * DIM * sizeof(float), stream);
    const int grid = ((B + 3) / 4) * 4;
    k_fallback<<<grid, BLOCK, 0, stream>>>(x, y, I, J, K, C, z, n, B);
    return;
  }

  uint32* cur = (uint32*)d_ws;
  int2* IJC = (int2*)((char*)d_ws + cur_bytes);

  k_zero<<<(ZERO_VECS + BLOCK - 1) / BLOCK, BLOCK, 0, stream>>>((int4*)d_ws);
  k_scatter<<<(n + BLOCK - 1) / BLOCK, BLOCK, 0, stream>>>(I, J, K, C, cur, IJC, n);

  const int groups = (B + ROWS - 1) / ROWS;
  k_main<<<groups * KS, BLOCK, 0, stream>>>(x, y, IJC, cur, z, B);
}